// Round 12
// baseline (216.066 us; speedup 1.0000x reference)
//
#include <hip/hip_runtime.h>
#include <stdint.h>

// B=4, C=O=320, H=W=64 -> HW=4096, N=16384 (b*4096+px), N2=32768 for Cc.
// Round 12: LDS-staged k_blend. r11 blend (~40us) was L3-gather-latency
// bound: 45 scattered 16B taps/thread into 94MB Z (> 32MB L2) = ~600cy
// each, ~7 in flight. Fix: one (k,og,b) Z plane = 64KB = exact LDS fit.
// Per k: stream full plane into LDS (coalesced global_load_lds, linear
// dest), barrier, gather taps via ds_read_b128 (short latency, 256B/cy).
// Column wrap-around is irrelevant: whole plane resident. Bit-identical.
// prep/zgemm/final unchanged (r10/r11-verified).
//   Z[(k,o), n] = sum_c w[o,c,k] x[c,n]   (GEMM: M=2880, N=16384, K=320)
//   dconv[o,p]  = sum_k sum_t wt_t(k,p) Z_k[o, idx_t(k,p)]      (k_blend)
//   h[o,p]      = sum_k Z_k[o, shift_k(p)] (conv3x3 = free from Z)
//
// Layouts:
//   Wr2 packed-8 K-major: elem(m,c) at ((c>>3)*2880 + m)*8 + (c&7), m=k*320+o.
//   Xb  packed-8:         elem(c,n) at ((c>>3)*16384 + n)*8 + (c&7).
//   Z   packed-8:         elem(m,n) at ((m>>3)*16384 + n)*8 + (m&7).
//   Cc  packed-8:         elem(o,n2) at (o>>3)*32768*8 + n2*8 + (o&7);
//                         n2<16384 dconv+bias, n2>=16384 h+bias.
//   oIdx: 2 u32 per (k,p); oW: float4 weights (validity folded).
//
// ws layout (bytes):
//   Cc 0..25,165,824 | Wr2 ..27,377,664 | W2 ..27,869,184 | oIdx ..28,164,096
//   oWt ..28,753,920 | Xb @28,758,016 | Z @39,909,376 (+94,371,840)

typedef __attribute__((ext_vector_type(4))) float f32x4;
typedef __attribute__((ext_vector_type(8))) short bf16x8;

typedef __attribute__((address_space(1))) const unsigned int uint_as1;
typedef __attribute__((address_space(3))) unsigned int uint_as3;

__device__ __forceinline__ void gl_lds16(const void* g, void* l) {
    __builtin_amdgcn_global_load_lds((uint_as1*)g, (uint_as3*)l, 16, 0, 0);
}

__device__ __forceinline__ unsigned short f2b(float f) {
    union { float f; uint32_t u; } v; v.f = f;
    uint32_t r = (v.u + 0x7FFFu + ((v.u >> 16) & 1u)) >> 16;
    return (unsigned short)r;
}
__device__ __forceinline__ float b2f(unsigned short h) {
    union { uint32_t u; float f; } v; v.u = ((uint32_t)h) << 16;
    return v.f;
}
__device__ __forceinline__ float b2f_lo(uint32_t u) {
    union { uint32_t u; float f; } v; v.u = u << 16;
    return v.f;
}
__device__ __forceinline__ float b2f_hi(uint32_t u) {
    union { uint32_t u; float f; } v; v.u = u & 0xFFFF0000u;
    return v.f;
}
__device__ __forceinline__ uint32_t pack2(float lo, float hi) {
    return (uint32_t)f2b(lo) | ((uint32_t)f2b(hi) << 16);
}

#define TAP8(AC, tv, wvx) \
    AC[0] += wvx * b2f_lo((uint32_t)tv.x); AC[1] += wvx * b2f_hi((uint32_t)tv.x); \
    AC[2] += wvx * b2f_lo((uint32_t)tv.y); AC[3] += wvx * b2f_hi((uint32_t)tv.y); \
    AC[4] += wvx * b2f_lo((uint32_t)tv.z); AC[5] += wvx * b2f_hi((uint32_t)tv.z); \
    AC[6] += wvx * b2f_lo((uint32_t)tv.w); AC[7] += wvx * b2f_hi((uint32_t)tv.w);

// ---------------------------------------------------------------------------
// Fused prep. [0,144) bilinear recs; [144,594) Wr2 (ushort8 coalesced);
// [594,1554) W2 (float4-vectorized reduce); [1554,2194) x->Xb pack.
__global__ __launch_bounds__(256) void k_prep(const float* __restrict__ off,
                                              const float* __restrict__ w,
                                              const float* __restrict__ wd,
                                              const float* __restrict__ wu,
                                              const float* __restrict__ x,
                                              uint32_t* __restrict__ oIdx,
                                              float* __restrict__ oW,
                                              unsigned short* __restrict__ Wr2,
                                              unsigned short* __restrict__ W2,
                                              unsigned short* __restrict__ Xb)
{
    const int bx = blockIdx.x, tid = threadIdx.x;
    if (bx < 144) {
        int gid = bx * 256 + tid;                    // 9*4096 exact
        int k = gid >> 12;
        int p = gid & 4095;
        int i = p >> 6, j = p & 63;
        float dy = off[(2 * k) * 4096 + p];
        float dx = off[(2 * k + 1) * 4096 + p];
        float py = (float)(i - 1 + k / 3) + dy;
        float px = (float)(j - 1 + k % 3) + dx;
        float fy = floorf(py), fx = floorf(px);
        float wy = py - fy, wx = px - fx;
        fy = fminf(fmaxf(fy, -100.f), 100.f);
        fx = fminf(fmaxf(fx, -100.f), 100.f);
        int y0 = (int)fy, x0 = (int)fx;
        float vy0 = (y0 >= 0 && y0 < 64) ? 1.f : 0.f;
        float vy1 = (y0 >= -1 && y0 < 63) ? 1.f : 0.f;
        float vx0 = (x0 >= 0 && x0 < 64) ? 1.f : 0.f;
        float vx1 = (x0 >= -1 && x0 < 63) ? 1.f : 0.f;
        float w00 = (1.f - wy) * (1.f - wx) * vy0 * vx0;
        float w01 = (1.f - wy) * wx * vy0 * vx1;
        float w10 = wy * (1.f - wx) * vy1 * vx0;
        float w11 = wy * wx * vy1 * vx1;
        int ya = min(max(y0, 0), 63), yb = min(max(y0 + 1, 0), 63);
        int xa = min(max(x0, 0), 63), xb = min(max(x0 + 1, 0), 63);
        oIdx[gid * 2 + 0] = (uint32_t)(ya * 64 + xa) | ((uint32_t)(ya * 64 + xb) << 16);
        oIdx[gid * 2 + 1] = (uint32_t)(yb * 64 + xa) | ((uint32_t)(yb * 64 + xb) << 16);
        oW[gid * 4 + 0] = w00;
        oW[gid * 4 + 1] = w01;
        oW[gid * 4 + 2] = w10;
        oW[gid * 4 + 3] = w11;
    } else if (bx < 594) {
        // Wr2: one thread per (cb, m); m = k*320+o; coalesced ushort8 store.
        int gid = (bx - 144) * 256 + tid;            // 40*2880 exact
        int cb = gid / 2880, m = gid - cb * 2880;
        int k = m / 320, o = m - k * 320;
        float v[8];
        #pragma unroll
        for (int cl = 0; cl < 8; ++cl) {
            int c = cb * 8 + cl;
            v[cl] = w[((size_t)o * 320 + c) * 9 + k];
        }
        int4 st;
        st.x = (int)pack2(v[0], v[1]);
        st.y = (int)pack2(v[2], v[3]);
        st.z = (int)pack2(v[4], v[5]);
        st.w = (int)pack2(v[6], v[7]);
        *(int4*)(Wr2 + (size_t)gid * 8) = st;
    } else if (bx < 1554) {
        // W2 = wu @ wd, float4-vectorized over l (4 indep chains).
        int gid = (bx - 594) * 256 + tid;            // 384*640 exact
        int o = gid / 640, kk2 = gid % 640;
        float a0 = 0.f, a1 = 0.f, a2 = 0.f, a3 = 0.f;
        if (o < 320) {
            const float* wuo = wu + (size_t)o * 320;
            for (int l = 0; l < 320; l += 4) {
                float4 u4 = *(const float4*)(wuo + l);
                a0 += u4.x * wd[(size_t)(l + 0) * 640 + kk2];
                a1 += u4.y * wd[(size_t)(l + 1) * 640 + kk2];
                a2 += u4.z * wd[(size_t)(l + 2) * 640 + kk2];
                a3 += u4.w * wd[(size_t)(l + 3) * 640 + kk2];
            }
        }
        W2[(size_t)((kk2 >> 3) * 384 + o) * 8 + (kk2 & 7)] = f2b((a0 + a1) + (a2 + a3));
    } else {
        // Pack x -> Xb (bf16 packed-8): elem(c,n) at ((c>>3)*16384+n)*8+(c&7).
        int bz = bx - 1554;                          // 640 blocks
        int sp = bz & 3, rest = bz >> 2;
        int gl = rest % 40, b = rest / 40;
        const float* xb = x + ((size_t)b * 320 + gl * 8) * 4096;
        unsigned short* xpb = Xb + ((size_t)gl * 16384 + b * 4096) * 8;
        #pragma unroll
        for (int i = 0; i < 4; ++i) {
            int px = sp * 1024 + i * 256 + tid;
            float v0 = xb[0 * 4096 + px], v1 = xb[1 * 4096 + px];
            float v2 = xb[2 * 4096 + px], v3 = xb[3 * 4096 + px];
            float v4 = xb[4 * 4096 + px], v5 = xb[5 * 4096 + px];
            float v6 = xb[6 * 4096 + px], v7 = xb[7 * 4096 + px];
            int4 st;
            st.x = (int)pack2(v0, v1);
            st.y = (int)pack2(v2, v3);
            st.z = (int)pack2(v4, v5);
            st.w = (int)pack2(v6, v7);
            *(int4*)(xpb + (size_t)px * 8) = st;
        }
    }
}

// ---------------------------------------------------------------------------
// Z-GEMM (r10-verified): A-fragments global->VGPR (L2/L3-hot Wr2); B via
// dbuf LDS (32 KB). M=2880 (18x160), N=16384, K=320 as 5 BK=64 steps.
// BM=160, BN=128, 4 waves 2Mx2N, per-wave 80x64, acc 5x4. 3 blk/CU.
__global__ __launch_bounds__(256, 3) void k_zgemm(const unsigned short* __restrict__ Xb,
                                                  const unsigned short* __restrict__ Wr2,
                                                  unsigned short* __restrict__ Z)
{
    __shared__ __align__(16) unsigned short Bs[2][8 * 128 * 8];   // 2 x 16 KB
    const int tid = threadIdx.x;
    const int n0 = blockIdx.x * 128, m0 = blockIdx.y * 160;
    const int lane = tid & 63, w = tid >> 6;
    const int wm = w & 1, wn = w >> 1;
    const int quad = lane >> 4, nl = lane & 15;
    const unsigned short* Abase = Wr2 + ((size_t)quad * 2880 + m0 + wm * 80 + nl) * 8;

#define STAGE_B(buf, s1) do { \
    _Pragma("unroll") \
    for (int q_ = 0; q_ < 4; ++q_) { \
        int u_ = tid + q_ * 256; \
        int row_ = u_ >> 7, nn_ = n0 + (u_ & 127); \
        gl_lds16(Xb + ((size_t)((s1) * 8 + row_) * 16384 + nn_) * 8, &Bs[buf][u_ * 8]); \
    } \
} while (0)

    f32x4 acc[5][4];
    #pragma unroll
    for (int mt = 0; mt < 5; ++mt)
        #pragma unroll
        for (int nt = 0; nt < 4; ++nt)
            acc[mt][nt] = 0.f;

    STAGE_B(0, 0);
    asm volatile("s_waitcnt vmcnt(0)" ::: "memory");
    __builtin_amdgcn_s_barrier();
    __builtin_amdgcn_sched_barrier(0);

    for (int s = 0; s < 5; ++s) {
        const int p = s & 1, np = p ^ 1;
        bf16x8 a[2][5];
        #pragma unroll
        for (int kc = 0; kc < 2; ++kc)
            #pragma unroll
            for (int mt = 0; mt < 5; ++mt)
                a[kc][mt] = *(const bf16x8*)(Abase
                    + ((size_t)((s * 8 + kc * 4) * 2880) + mt * 16) * 8);
        if (s < 4) STAGE_B(np, s + 1);
        __builtin_amdgcn_sched_barrier(0);
        #pragma unroll
        for (int kc = 0; kc < 2; ++kc) {
            bf16x8 bf[4];
            #pragma unroll
            for (int nt = 0; nt < 4; ++nt)
                bf[nt] = *(const bf16x8*)&Bs[p][((kc * 4 + quad) * 128 + wn * 64 + nt * 16 + nl) * 8];
            #pragma unroll
            for (int mt = 0; mt < 5; ++mt)
                #pragma unroll
                for (int nt = 0; nt < 4; ++nt)
                    acc[mt][nt] = __builtin_amdgcn_mfma_f32_16x16x32_bf16(a[kc][mt], bf[nt], acc[mt][nt], 0, 0, 0);
        }
        asm volatile("s_waitcnt vmcnt(0)" ::: "memory");
        __builtin_amdgcn_s_barrier();
        __builtin_amdgcn_sched_barrier(0);
    }

    // Epilogue: pack to Z (no bias). m index in [0,2880).
    #pragma unroll
    for (int mt = 0; mt < 5; ++mt) {
        int o0m = m0 + wm * 80 + mt * 16 + quad * 4;
        #pragma unroll
        for (int nt = 0; nt < 4; ++nt) {
            int n2 = n0 + wn * 64 + nt * 16 + nl;
            unsigned short* pp = Z + ((size_t)(o0m >> 3) * 16384 + n2) * 8 + (o0m & 7);
            ushort4 st;
            st.x = f2b(acc[mt][nt][0]);
            st.y = f2b(acc[mt][nt][1]);
            st.z = f2b(acc[mt][nt][2]);
            st.w = f2b(acc[mt][nt][3]);
            *(ushort4*)pp = st;
        }
    }
#undef STAGE_B
}

// ---------------------------------------------------------------------------
// Blend (round 12, LDS-staged): block = (sp in 4, og, b), 512 threads;
// each thread owns 2 px (lpx = tid, tid+512 within the 1024-px slice).
// Per k: stream full 64KB Z plane (k*40+og, b) into LDS (coalesced
// global_load_lds, linear dest), barrier, gather 5 taps/px from LDS,
// accumulate; barrier; next k. Indices identical to r11 -> bit-identical.
// LDS 64KB -> 2 blk/CU x 8 waves = 16 waves/CU.
__global__ __launch_bounds__(512) void k_blend(const unsigned short* __restrict__ Z,
                                               const uint32_t* __restrict__ oIdx,
                                               const float* __restrict__ oW,
                                               const float* __restrict__ bias,
                                               unsigned short* __restrict__ Cc)
{
    __shared__ __align__(16) unsigned short Zp[4096 * 8];   // 64 KB: full plane
    const int tid = threadIdx.x;
    const int sp = blockIdx.x, og = blockIdx.y, b = blockIdx.z;
    const int px0 = sp * 1024;

    float ac[2][8], ah[2][8];
    {
        float4 b0 = *(const float4*)&bias[og * 8];
        float4 b1 = *(const float4*)&bias[og * 8 + 4];
        #pragma unroll
        for (int j = 0; j < 2; ++j) {
            ac[j][0] = b0.x; ac[j][1] = b0.y; ac[j][2] = b0.z; ac[j][3] = b0.w;
            ac[j][4] = b1.x; ac[j][5] = b1.y; ac[j][6] = b1.z; ac[j][7] = b1.w;
            #pragma unroll
            for (int q = 0; q < 8; ++q) ah[j][q] = ac[j][q];
        }
    }

    for (int k = 0; k < 9; ++k) {
        // Stage full plane (4096 x 16B) into LDS; linear dest, coalesced src.
        const unsigned short* Zplane = Z + ((size_t)(k * 40 + og) * 16384 + b * 4096) * 8;
        #pragma unroll
        for (int q = 0; q < 8; ++q) {
            int u = tid + q * 512;
            gl_lds16(Zplane + (size_t)u * 8, &Zp[u * 8]);
        }
        asm volatile("s_waitcnt vmcnt(0)" ::: "memory");
        __builtin_amdgcn_s_barrier();

        #pragma unroll
        for (int j = 0; j < 2; ++j) {
            int lpx = j * 512 + tid;
            int px = px0 + lpx;
            int gi = (k << 12) + px;
            uint32_t i0 = oIdx[gi * 2];
            uint32_t i1 = oIdx[gi * 2 + 1];
            float4 wv = *(const float4*)&oW[(size_t)gi * 4];
            int r = px >> 6, c0 = px & 63;
            int rr = r + k / 3 - 1, cc = c0 + k % 3 - 1;
            bool valid = (rr >= 0) & (rr < 64) & (cc >= 0) & (cc < 64);
            int hidx = valid ? (rr * 64 + cc) : 0;
            float hw = valid ? 1.f : 0.f;
            int4 t0 = *(const int4*)&Zp[(size_t)(i0 & 0xFFFFu) * 8];
            int4 t1 = *(const int4*)&Zp[(size_t)(i0 >> 16) * 8];
            int4 t2 = *(const int4*)&Zp[(size_t)(i1 & 0xFFFFu) * 8];
            int4 t3 = *(const int4*)&Zp[(size_t)(i1 >> 16) * 8];
            int4 th = *(const int4*)&Zp[(size_t)hidx * 8];
            TAP8(ac[j], t0, wv.x) TAP8(ac[j], t1, wv.y)
            TAP8(ac[j], t2, wv.z) TAP8(ac[j], t3, wv.w)
            TAP8(ah[j], th, hw)
        }
        __builtin_amdgcn_s_barrier();   // all gathers done before next stage
    }

    #pragma unroll
    for (int j = 0; j < 2; ++j) {
        int px = px0 + j * 512 + tid;
        int4 sd, sh;
        sd.x = (int)pack2(ac[j][0], ac[j][1]); sd.y = (int)pack2(ac[j][2], ac[j][3]);
        sd.z = (int)pack2(ac[j][4], ac[j][5]); sd.w = (int)pack2(ac[j][6], ac[j][7]);
        sh.x = (int)pack2(ah[j][0], ah[j][1]); sh.y = (int)pack2(ah[j][2], ah[j][3]);
        sh.z = (int)pack2(ah[j][4], ah[j][5]); sh.w = (int)pack2(ah[j][6], ah[j][7]);
        unsigned short* cp = Cc + ((size_t)og * 32768 + b * 4096 + px) * 8;
        *(int4*)cp = sd;
        *(int4*)(cp + 16384 * 8) = sh;
    }
}

// ---------------------------------------------------------------------------
// Final: out = h + scale * (W2 x [dconv; h]), K=640 as 10 BK=64 steps.
// r2-style dbuf 2-phase, BM=160 x BN=64, 4 waves 2Mx2N, per-wave 80x32,
// acc 5x2. LDS 56 KB -> 2 blk/CU; grid 256x2 = 512 = 2/CU exact.
__global__ __launch_bounds__(256) void k_final(const unsigned short* __restrict__ W2,
                                               const unsigned short* __restrict__ Cc,
                                               const float* __restrict__ scale,
                                               float* __restrict__ out)
{
    __shared__ __align__(16) unsigned short As[2][8 * 160 * 8];   // 2 x 20 KB
    __shared__ __align__(16) unsigned short Bs[2][8 * 64 * 8];    // 2 x 8 KB
    const int tid = threadIdx.x;
    const int n0 = blockIdx.x * 64, m0 = blockIdx.y * 160;
    const int lane = tid & 63, w = tid >> 6;
    const int wm = w & 1, wn = w >> 1;
    const int quad = lane >> 4, nl = lane & 15;

#define STAGEF(buf, s1) do { \
    _Pragma("unroll") \
    for (int q_ = 0; q_ < 5; ++q_) { \
        int u_ = tid + q_ * 256; \
        int kq_ = u_ / 160, m_ = u_ - kq_ * 160; \
        gl_lds16(W2 + ((size_t)(((s1) * 8 + kq_) * 384 + m0 + m_)) * 8, &As[buf][u_ * 8]); \
    } \
    { \
        int h_off_ = ((s1) < 5) ? 0 : 16384; \
        int gq_ = ((s1) < 5) ? (s1) * 8 : ((s1) - 5) * 8; \
        _Pragma("unroll") \
        for (int q_ = 0; q_ < 2; ++q_) { \
            int u_ = tid + q_ * 256; \
            int row_ = u_ >> 6, nn_ = n0 + (u_ & 63); \
            gl_lds16(Cc + ((size_t)(gq_ + row_) * 32768 + h_off_ + nn_) * 8, &Bs[buf][u_ * 8]); \
        } \
    } \
} while (0)

    f32x4 acc[5][2];
    #pragma unroll
    for (int mt = 0; mt < 5; ++mt)
        #pragma unroll
        for (int nt = 0; nt < 2; ++nt)
            acc[mt][nt] = 0.f;

    STAGEF(0, 0);
    asm volatile("s_waitcnt vmcnt(0)" ::: "memory");
    __builtin_amdgcn_s_barrier();
    __builtin_amdgcn_sched_barrier(0);

    for (int s = 0; s < 10; ++s) {
        const int p = s & 1, np = p ^ 1;
        if (s < 9) STAGEF(np, s + 1);
        __builtin_amdgcn_sched_barrier(0);
        #pragma unroll
        for (int kc = 0; kc < 2; ++kc) {
            bf16x8 a[5], bf[2];
            #pragma unroll
            for (int mt = 0; mt < 5; ++mt)
                a[mt] = *(const bf16x8*)&As[p][((kc * 4 + quad) * 160 + wm * 80 + mt * 16 + nl) * 8];
            #pragma unroll
            for (int nt = 0; nt < 2; ++nt)
                bf[nt] = *(const bf16x8*)&Bs[p][((kc * 4 + quad) * 64 + wn * 32 + nt * 16 + nl) * 8];
            #pragma unroll
            for (int mt = 0; mt < 5; ++mt)
                #pragma unroll
                for (int nt = 0; nt < 2; ++nt)
                    acc[mt][nt] = __builtin_amdgcn_mfma_f32_16x16x32_bf16(a[mt], bf[nt], acc[mt][nt], 0, 0, 0);
        }
        asm volatile("s_waitcnt vmcnt(0)" ::: "memory");
        __builtin_amdgcn_s_barrier();
        __builtin_amdgcn_sched_barrier(0);
    }

    float sc = scale[0];
    #pragma unroll
    for (int mt = 0; mt < 5; ++mt) {
        int o0 = m0 + wm * 80 + mt * 16 + quad * 4;
        #pragma unroll
        for (int nt = 0; nt < 2; ++nt) {
            int n = n0 + wn * 32 + nt * 16 + nl;
            int b = n >> 12, px = n & 4095;
            ushort4 hv = *(const ushort4*)(Cc + ((size_t)(o0 >> 3) * 32768 + n + 16384) * 8 + (o0 & 7));
            size_t base = ((size_t)(b * 320 + o0)) * 4096 + px;
            out[base]            = b2f(hv.x) + sc * acc[mt][nt][0];
            out[base + 4096]     = b2f(hv.y) + sc * acc[mt][nt][1];
            out[base + 2 * 4096] = b2f(hv.z) + sc * acc[mt][nt][2];
            out[base + 3 * 4096] = b2f(hv.w) + sc * acc[mt][nt][3];
        }
    }
#undef STAGEF
}

// ---------------------------------------------------------------------------
extern "C" void kernel_launch(void* const* d_in, const int* in_sizes, int n_in,
                              void* d_out, int out_size, void* d_ws, size_t ws_size,
                              hipStream_t stream)
{
    const float* x      = (const float*)d_in[0];
    const float* weight = (const float*)d_in[1];
    const float* bias   = (const float*)d_in[2];
    const float* w_down = (const float*)d_in[3];
    const float* w_up   = (const float*)d_in[4];
    const float* scale  = (const float*)d_in[5];
    const float* offset = (const float*)d_in[6];
    char* ws = (char*)d_ws;
    unsigned short* Cc    = (unsigned short*)(ws + 0);
    unsigned short* Wr2   = (unsigned short*)(ws + 25165824);
    unsigned short* W2    = (unsigned short*)(ws + 27377664);
    uint32_t*       oI    = (uint32_t*)(ws + 27869184);
    float*          oWt   = (float*)(ws + 28164096);
    unsigned short* Xb    = (unsigned short*)(ws + 28758016);
    unsigned short* Z     = (unsigned short*)(ws + 39909376);
    float* out = (float*)d_out;

    hipLaunchKernelGGL(k_prep, dim3(2194), dim3(256), 0, stream,
                       offset, weight, w_down, w_up, x, oI, oWt, Wr2, W2, Xb);
    hipLaunchKernelGGL(k_zgemm, dim3(128, 18), dim3(256), 0, stream,
                       Xb, Wr2, Z);
    hipLaunchKernelGGL(k_blend, dim3(4, 40, 4), dim3(512), 0, stream,
                       Z, oI, oWt, bias, Cc);
    hipLaunchKernelGGL(k_final, dim3(256, 2), dim3(256), 0, stream,
                       W2, Cc, scale, out);
}

// Round 13
// 204.713 us; speedup vs baseline: 1.0555x; 1.0555x over previous
//
#include <hip/hip_runtime.h>
#include <stdint.h>

// B=4, C=O=320, H=W=64 -> HW=4096, N=16384 (b*4096+px), N2=32768 for Cc.
// Round 13: k_blend staged-once. r12's sp-split staged every plane 4x
// (FETCH 186 MB -> HBM-bound, 66us). Now block = (og,b): grid (40,4)=160
// blocks, 1024 threads, 4 px/thread; each (k,og,b) 64KB plane staged
// EXACTLY once; double-buffered (2x64KB=128KB LDS) so stage(k+1) overlaps
// gather(k). Z traffic 377->94 MB (read-once, L3-hot). Indices unchanged
// -> bit-identical. prep/zgemm/final unchanged (r10/r11-verified).
//   Z[(k,o), n] = sum_c w[o,c,k] x[c,n]   (GEMM: M=2880, N=16384, K=320)
//   dconv[o,p]  = sum_k sum_t wt_t(k,p) Z_k[o, idx_t(k,p)]      (k_blend)
//   h[o,p]      = sum_k Z_k[o, shift_k(p)] (conv3x3 = free from Z)
//
// Layouts:
//   Wr2 packed-8 K-major: elem(m,c) at ((c>>3)*2880 + m)*8 + (c&7), m=k*320+o.
//   Xb  packed-8:         elem(c,n) at ((c>>3)*16384 + n)*8 + (c&7).
//   Z   packed-8:         elem(m,n) at ((m>>3)*16384 + n)*8 + (m&7).
//   Cc  packed-8:         elem(o,n2) at (o>>3)*32768*8 + n2*8 + (o&7);
//                         n2<16384 dconv+bias, n2>=16384 h+bias.
//   oIdx: 2 u32 per (k,p); oW: float4 weights (validity folded).
//
// ws layout (bytes):
//   Cc 0..25,165,824 | Wr2 ..27,377,664 | W2 ..27,869,184 | oIdx ..28,164,096
//   oWt ..28,753,920 | Xb @28,758,016 | Z @39,909,376 (+94,371,840)

typedef __attribute__((ext_vector_type(4))) float f32x4;
typedef __attribute__((ext_vector_type(8))) short bf16x8;

typedef __attribute__((address_space(1))) const unsigned int uint_as1;
typedef __attribute__((address_space(3))) unsigned int uint_as3;

__device__ __forceinline__ void gl_lds16(const void* g, void* l) {
    __builtin_amdgcn_global_load_lds((uint_as1*)g, (uint_as3*)l, 16, 0, 0);
}

__device__ __forceinline__ unsigned short f2b(float f) {
    union { float f; uint32_t u; } v; v.f = f;
    uint32_t r = (v.u + 0x7FFFu + ((v.u >> 16) & 1u)) >> 16;
    return (unsigned short)r;
}
__device__ __forceinline__ float b2f(unsigned short h) {
    union { uint32_t u; float f; } v; v.u = ((uint32_t)h) << 16;
    return v.f;
}
__device__ __forceinline__ float b2f_lo(uint32_t u) {
    union { uint32_t u; float f; } v; v.u = u << 16;
    return v.f;
}
__device__ __forceinline__ float b2f_hi(uint32_t u) {
    union { uint32_t u; float f; } v; v.u = u & 0xFFFF0000u;
    return v.f;
}
__device__ __forceinline__ uint32_t pack2(float lo, float hi) {
    return (uint32_t)f2b(lo) | ((uint32_t)f2b(hi) << 16);
}

#define TAP8(AC, tv, wvx) \
    AC[0] += wvx * b2f_lo((uint32_t)tv.x); AC[1] += wvx * b2f_hi((uint32_t)tv.x); \
    AC[2] += wvx * b2f_lo((uint32_t)tv.y); AC[3] += wvx * b2f_hi((uint32_t)tv.y); \
    AC[4] += wvx * b2f_lo((uint32_t)tv.z); AC[5] += wvx * b2f_hi((uint32_t)tv.z); \
    AC[6] += wvx * b2f_lo((uint32_t)tv.w); AC[7] += wvx * b2f_hi((uint32_t)tv.w);

// ---------------------------------------------------------------------------
// Fused prep. [0,144) bilinear recs; [144,594) Wr2 (ushort8 coalesced);
// [594,1554) W2 (float4-vectorized reduce); [1554,2194) x->Xb pack.
__global__ __launch_bounds__(256) void k_prep(const float* __restrict__ off,
                                              const float* __restrict__ w,
                                              const float* __restrict__ wd,
                                              const float* __restrict__ wu,
                                              const float* __restrict__ x,
                                              uint32_t* __restrict__ oIdx,
                                              float* __restrict__ oW,
                                              unsigned short* __restrict__ Wr2,
                                              unsigned short* __restrict__ W2,
                                              unsigned short* __restrict__ Xb)
{
    const int bx = blockIdx.x, tid = threadIdx.x;
    if (bx < 144) {
        int gid = bx * 256 + tid;                    // 9*4096 exact
        int k = gid >> 12;
        int p = gid & 4095;
        int i = p >> 6, j = p & 63;
        float dy = off[(2 * k) * 4096 + p];
        float dx = off[(2 * k + 1) * 4096 + p];
        float py = (float)(i - 1 + k / 3) + dy;
        float px = (float)(j - 1 + k % 3) + dx;
        float fy = floorf(py), fx = floorf(px);
        float wy = py - fy, wx = px - fx;
        fy = fminf(fmaxf(fy, -100.f), 100.f);
        fx = fminf(fmaxf(fx, -100.f), 100.f);
        int y0 = (int)fy, x0 = (int)fx;
        float vy0 = (y0 >= 0 && y0 < 64) ? 1.f : 0.f;
        float vy1 = (y0 >= -1 && y0 < 63) ? 1.f : 0.f;
        float vx0 = (x0 >= 0 && x0 < 64) ? 1.f : 0.f;
        float vx1 = (x0 >= -1 && x0 < 63) ? 1.f : 0.f;
        float w00 = (1.f - wy) * (1.f - wx) * vy0 * vx0;
        float w01 = (1.f - wy) * wx * vy0 * vx1;
        float w10 = wy * (1.f - wx) * vy1 * vx0;
        float w11 = wy * wx * vy1 * vx1;
        int ya = min(max(y0, 0), 63), yb = min(max(y0 + 1, 0), 63);
        int xa = min(max(x0, 0), 63), xb = min(max(x0 + 1, 0), 63);
        oIdx[gid * 2 + 0] = (uint32_t)(ya * 64 + xa) | ((uint32_t)(ya * 64 + xb) << 16);
        oIdx[gid * 2 + 1] = (uint32_t)(yb * 64 + xa) | ((uint32_t)(yb * 64 + xb) << 16);
        oW[gid * 4 + 0] = w00;
        oW[gid * 4 + 1] = w01;
        oW[gid * 4 + 2] = w10;
        oW[gid * 4 + 3] = w11;
    } else if (bx < 594) {
        // Wr2: one thread per (cb, m); m = k*320+o; coalesced ushort8 store.
        int gid = (bx - 144) * 256 + tid;            // 40*2880 exact
        int cb = gid / 2880, m = gid - cb * 2880;
        int k = m / 320, o = m - k * 320;
        float v[8];
        #pragma unroll
        for (int cl = 0; cl < 8; ++cl) {
            int c = cb * 8 + cl;
            v[cl] = w[((size_t)o * 320 + c) * 9 + k];
        }
        int4 st;
        st.x = (int)pack2(v[0], v[1]);
        st.y = (int)pack2(v[2], v[3]);
        st.z = (int)pack2(v[4], v[5]);
        st.w = (int)pack2(v[6], v[7]);
        *(int4*)(Wr2 + (size_t)gid * 8) = st;
    } else if (bx < 1554) {
        // W2 = wu @ wd, float4-vectorized over l (4 indep chains).
        int gid = (bx - 594) * 256 + tid;            // 384*640 exact
        int o = gid / 640, kk2 = gid % 640;
        float a0 = 0.f, a1 = 0.f, a2 = 0.f, a3 = 0.f;
        if (o < 320) {
            const float* wuo = wu + (size_t)o * 320;
            for (int l = 0; l < 320; l += 4) {
                float4 u4 = *(const float4*)(wuo + l);
                a0 += u4.x * wd[(size_t)(l + 0) * 640 + kk2];
                a1 += u4.y * wd[(size_t)(l + 1) * 640 + kk2];
                a2 += u4.z * wd[(size_t)(l + 2) * 640 + kk2];
                a3 += u4.w * wd[(size_t)(l + 3) * 640 + kk2];
            }
        }
        W2[(size_t)((kk2 >> 3) * 384 + o) * 8 + (kk2 & 7)] = f2b((a0 + a1) + (a2 + a3));
    } else {
        // Pack x -> Xb (bf16 packed-8): elem(c,n) at ((c>>3)*16384+n)*8+(c&7).
        int bz = bx - 1554;                          // 640 blocks
        int sp = bz & 3, rest = bz >> 2;
        int gl = rest % 40, b = rest / 40;
        const float* xb = x + ((size_t)b * 320 + gl * 8) * 4096;
        unsigned short* xpb = Xb + ((size_t)gl * 16384 + b * 4096) * 8;
        #pragma unroll
        for (int i = 0; i < 4; ++i) {
            int px = sp * 1024 + i * 256 + tid;
            float v0 = xb[0 * 4096 + px], v1 = xb[1 * 4096 + px];
            float v2 = xb[2 * 4096 + px], v3 = xb[3 * 4096 + px];
            float v4 = xb[4 * 4096 + px], v5 = xb[5 * 4096 + px];
            float v6 = xb[6 * 4096 + px], v7 = xb[7 * 4096 + px];
            int4 st;
            st.x = (int)pack2(v0, v1);
            st.y = (int)pack2(v2, v3);
            st.z = (int)pack2(v4, v5);
            st.w = (int)pack2(v6, v7);
            *(int4*)(xpb + (size_t)px * 8) = st;
        }
    }
}

// ---------------------------------------------------------------------------
// Z-GEMM (r10-verified): A-fragments global->VGPR (L2/L3-hot Wr2); B via
// dbuf LDS (32 KB). M=2880 (18x160), N=16384, K=320 as 5 BK=64 steps.
// BM=160, BN=128, 4 waves 2Mx2N, per-wave 80x64, acc 5x4. 3 blk/CU.
__global__ __launch_bounds__(256, 3) void k_zgemm(const unsigned short* __restrict__ Xb,
                                                  const unsigned short* __restrict__ Wr2,
                                                  unsigned short* __restrict__ Z)
{
    __shared__ __align__(16) unsigned short Bs[2][8 * 128 * 8];   // 2 x 16 KB
    const int tid = threadIdx.x;
    const int n0 = blockIdx.x * 128, m0 = blockIdx.y * 160;
    const int lane = tid & 63, w = tid >> 6;
    const int wm = w & 1, wn = w >> 1;
    const int quad = lane >> 4, nl = lane & 15;
    const unsigned short* Abase = Wr2 + ((size_t)quad * 2880 + m0 + wm * 80 + nl) * 8;

#define STAGE_B(buf, s1) do { \
    _Pragma("unroll") \
    for (int q_ = 0; q_ < 4; ++q_) { \
        int u_ = tid + q_ * 256; \
        int row_ = u_ >> 7, nn_ = n0 + (u_ & 127); \
        gl_lds16(Xb + ((size_t)((s1) * 8 + row_) * 16384 + nn_) * 8, &Bs[buf][u_ * 8]); \
    } \
} while (0)

    f32x4 acc[5][4];
    #pragma unroll
    for (int mt = 0; mt < 5; ++mt)
        #pragma unroll
        for (int nt = 0; nt < 4; ++nt)
            acc[mt][nt] = 0.f;

    STAGE_B(0, 0);
    asm volatile("s_waitcnt vmcnt(0)" ::: "memory");
    __builtin_amdgcn_s_barrier();
    __builtin_amdgcn_sched_barrier(0);

    for (int s = 0; s < 5; ++s) {
        const int p = s & 1, np = p ^ 1;
        bf16x8 a[2][5];
        #pragma unroll
        for (int kc = 0; kc < 2; ++kc)
            #pragma unroll
            for (int mt = 0; mt < 5; ++mt)
                a[kc][mt] = *(const bf16x8*)(Abase
                    + ((size_t)((s * 8 + kc * 4) * 2880) + mt * 16) * 8);
        if (s < 4) STAGE_B(np, s + 1);
        __builtin_amdgcn_sched_barrier(0);
        #pragma unroll
        for (int kc = 0; kc < 2; ++kc) {
            bf16x8 bf[4];
            #pragma unroll
            for (int nt = 0; nt < 4; ++nt)
                bf[nt] = *(const bf16x8*)&Bs[p][((kc * 4 + quad) * 128 + wn * 64 + nt * 16 + nl) * 8];
            #pragma unroll
            for (int mt = 0; mt < 5; ++mt)
                #pragma unroll
                for (int nt = 0; nt < 4; ++nt)
                    acc[mt][nt] = __builtin_amdgcn_mfma_f32_16x16x32_bf16(a[kc][mt], bf[nt], acc[mt][nt], 0, 0, 0);
        }
        asm volatile("s_waitcnt vmcnt(0)" ::: "memory");
        __builtin_amdgcn_s_barrier();
        __builtin_amdgcn_sched_barrier(0);
    }

    // Epilogue: pack to Z (no bias). m index in [0,2880).
    #pragma unroll
    for (int mt = 0; mt < 5; ++mt) {
        int o0m = m0 + wm * 80 + mt * 16 + quad * 4;
        #pragma unroll
        for (int nt = 0; nt < 4; ++nt) {
            int n2 = n0 + wn * 64 + nt * 16 + nl;
            unsigned short* pp = Z + ((size_t)(o0m >> 3) * 16384 + n2) * 8 + (o0m & 7);
            ushort4 st;
            st.x = f2b(acc[mt][nt][0]);
            st.y = f2b(acc[mt][nt][1]);
            st.z = f2b(acc[mt][nt][2]);
            st.w = f2b(acc[mt][nt][3]);
            *(ushort4*)pp = st;
        }
    }
#undef STAGE_B
}

// ---------------------------------------------------------------------------
// Blend (round 13, staged-once + dbuf): block = (og, b), 1024 threads,
// 4 px/thread. Per k: issue stage of plane k+1 into buf np (coalesced
// global_load_lds, linear dest), gather 5 taps/px for k from buf p,
// vmcnt(0)+barrier. Each plane staged exactly once. LDS 2x64KB = 128KB.
__global__ __launch_bounds__(1024) void k_blend(const unsigned short* __restrict__ Z,
                                                const uint32_t* __restrict__ oIdx,
                                                const float* __restrict__ oW,
                                                const float* __restrict__ bias,
                                                unsigned short* __restrict__ Cc)
{
    __shared__ __align__(16) unsigned short Zp[2][4096 * 8];   // 2 x 64 KB
    const int tid = threadIdx.x;
    const int og = blockIdx.x, b = blockIdx.y;

#define STAGE_Z(buf, k1) do { \
    const unsigned short* Zplane_ = Z + ((size_t)((k1) * 40 + og) * 16384 + b * 4096) * 8; \
    _Pragma("unroll") \
    for (int q_ = 0; q_ < 4; ++q_) { \
        int u_ = tid + q_ * 1024; \
        gl_lds16(Zplane_ + (size_t)u_ * 8, &Zp[buf][u_ * 8]); \
    } \
} while (0)

    float ac[4][8], ah[4][8];
    {
        float4 b0 = *(const float4*)&bias[og * 8];
        float4 b1 = *(const float4*)&bias[og * 8 + 4];
        #pragma unroll
        for (int j = 0; j < 4; ++j) {
            ac[j][0] = b0.x; ac[j][1] = b0.y; ac[j][2] = b0.z; ac[j][3] = b0.w;
            ac[j][4] = b1.x; ac[j][5] = b1.y; ac[j][6] = b1.z; ac[j][7] = b1.w;
            #pragma unroll
            for (int q = 0; q < 8; ++q) ah[j][q] = ac[j][q];
        }
    }

    // Prologue: stage plane 0.
    STAGE_Z(0, 0);
    asm volatile("s_waitcnt vmcnt(0)" ::: "memory");
    __builtin_amdgcn_s_barrier();

    for (int k = 0; k < 9; ++k) {
        const int p = k & 1, np = p ^ 1;
        if (k < 8) STAGE_Z(np, k + 1);       // issue-early; hides under gather

        #pragma unroll
        for (int j = 0; j < 4; ++j) {
            int px = j * 1024 + tid;
            int gi = (k << 12) + px;
            uint32_t i0 = oIdx[gi * 2];
            uint32_t i1 = oIdx[gi * 2 + 1];
            float4 wv = *(const float4*)&oW[(size_t)gi * 4];
            int r = px >> 6, c0 = px & 63;
            int rr = r + k / 3 - 1, cc = c0 + k % 3 - 1;
            bool valid = (rr >= 0) & (rr < 64) & (cc >= 0) & (cc < 64);
            int hidx = valid ? (rr * 64 + cc) : 0;
            float hw = valid ? 1.f : 0.f;
            int4 t0 = *(const int4*)&Zp[p][(size_t)(i0 & 0xFFFFu) * 8];
            int4 t1 = *(const int4*)&Zp[p][(size_t)(i0 >> 16) * 8];
            int4 t2 = *(const int4*)&Zp[p][(size_t)(i1 & 0xFFFFu) * 8];
            int4 t3 = *(const int4*)&Zp[p][(size_t)(i1 >> 16) * 8];
            int4 th = *(const int4*)&Zp[p][(size_t)hidx * 8];
            TAP8(ac[j], t0, wv.x) TAP8(ac[j], t1, wv.y)
            TAP8(ac[j], t2, wv.z) TAP8(ac[j], t3, wv.w)
            TAP8(ah[j], th, hw)
        }
        // Staged plane k+1 must have landed AND all gathers of plane k done
        // before any wave overwrites buf p at iteration k+1.
        asm volatile("s_waitcnt vmcnt(0)" ::: "memory");
        __builtin_amdgcn_s_barrier();
    }

    #pragma unroll
    for (int j = 0; j < 4; ++j) {
        int px = j * 1024 + tid;
        int4 sd, sh;
        sd.x = (int)pack2(ac[j][0], ac[j][1]); sd.y = (int)pack2(ac[j][2], ac[j][3]);
        sd.z = (int)pack2(ac[j][4], ac[j][5]); sd.w = (int)pack2(ac[j][6], ac[j][7]);
        sh.x = (int)pack2(ah[j][0], ah[j][1]); sh.y = (int)pack2(ah[j][2], ah[j][3]);
        sh.z = (int)pack2(ah[j][4], ah[j][5]); sh.w = (int)pack2(ah[j][6], ah[j][7]);
        unsigned short* cp = Cc + ((size_t)og * 32768 + b * 4096 + px) * 8;
        *(int4*)cp = sd;
        *(int4*)(cp + 16384 * 8) = sh;
    }
#undef STAGE_Z
}

// ---------------------------------------------------------------------------
// Final: out = h + scale * (W2 x [dconv; h]), K=640 as 10 BK=64 steps.
// r2-style dbuf 2-phase, BM=160 x BN=64, 4 waves 2Mx2N, per-wave 80x32,
// acc 5x2. LDS 56 KB -> 2 blk/CU; grid 256x2 = 512 = 2/CU exact.
__global__ __launch_bounds__(256) void k_final(const unsigned short* __restrict__ W2,
                                               const unsigned short* __restrict__ Cc,
                                               const float* __restrict__ scale,
                                               float* __restrict__ out)
{
    __shared__ __align__(16) unsigned short As[2][8 * 160 * 8];   // 2 x 20 KB
    __shared__ __align__(16) unsigned short Bs[2][8 * 64 * 8];    // 2 x 8 KB
    const int tid = threadIdx.x;
    const int n0 = blockIdx.x * 64, m0 = blockIdx.y * 160;
    const int lane = tid & 63, w = tid >> 6;
    const int wm = w & 1, wn = w >> 1;
    const int quad = lane >> 4, nl = lane & 15;

#define STAGEF(buf, s1) do { \
    _Pragma("unroll") \
    for (int q_ = 0; q_ < 5; ++q_) { \
        int u_ = tid + q_ * 256; \
        int kq_ = u_ / 160, m_ = u_ - kq_ * 160; \
        gl_lds16(W2 + ((size_t)(((s1) * 8 + kq_) * 384 + m0 + m_)) * 8, &As[buf][u_ * 8]); \
    } \
    { \
        int h_off_ = ((s1) < 5) ? 0 : 16384; \
        int gq_ = ((s1) < 5) ? (s1) * 8 : ((s1) - 5) * 8; \
        _Pragma("unroll") \
        for (int q_ = 0; q_ < 2; ++q_) { \
            int u_ = tid + q_ * 256; \
            int row_ = u_ >> 6, nn_ = n0 + (u_ & 63); \
            gl_lds16(Cc + ((size_t)(gq_ + row_) * 32768 + h_off_ + nn_) * 8, &Bs[buf][u_ * 8]); \
        } \
    } \
} while (0)

    f32x4 acc[5][2];
    #pragma unroll
    for (int mt = 0; mt < 5; ++mt)
        #pragma unroll
        for (int nt = 0; nt < 2; ++nt)
            acc[mt][nt] = 0.f;

    STAGEF(0, 0);
    asm volatile("s_waitcnt vmcnt(0)" ::: "memory");
    __builtin_amdgcn_s_barrier();
    __builtin_amdgcn_sched_barrier(0);

    for (int s = 0; s < 10; ++s) {
        const int p = s & 1, np = p ^ 1;
        if (s < 9) STAGEF(np, s + 1);
        __builtin_amdgcn_sched_barrier(0);
        #pragma unroll
        for (int kc = 0; kc < 2; ++kc) {
            bf16x8 a[5], bf[2];
            #pragma unroll
            for (int mt = 0; mt < 5; ++mt)
                a[mt] = *(const bf16x8*)&As[p][((kc * 4 + quad) * 160 + wm * 80 + mt * 16 + nl) * 8];
            #pragma unroll
            for (int nt = 0; nt < 2; ++nt)
                bf[nt] = *(const bf16x8*)&Bs[p][((kc * 4 + quad) * 64 + wn * 32 + nt * 16 + nl) * 8];
            #pragma unroll
            for (int mt = 0; mt < 5; ++mt)
                #pragma unroll
                for (int nt = 0; nt < 2; ++nt)
                    acc[mt][nt] = __builtin_amdgcn_mfma_f32_16x16x32_bf16(a[mt], bf[nt], acc[mt][nt], 0, 0, 0);
        }
        asm volatile("s_waitcnt vmcnt(0)" ::: "memory");
        __builtin_amdgcn_s_barrier();
        __builtin_amdgcn_sched_barrier(0);
    }

    float sc = scale[0];
    #pragma unroll
    for (int mt = 0; mt < 5; ++mt) {
        int o0 = m0 + wm * 80 + mt * 16 + quad * 4;
        #pragma unroll
        for (int nt = 0; nt < 2; ++nt) {
            int n = n0 + wn * 32 + nt * 16 + nl;
            int b = n >> 12, px = n & 4095;
            ushort4 hv = *(const ushort4*)(Cc + ((size_t)(o0 >> 3) * 32768 + n + 16384) * 8 + (o0 & 7));
            size_t base = ((size_t)(b * 320 + o0)) * 4096 + px;
            out[base]            = b2f(hv.x) + sc * acc[mt][nt][0];
            out[base + 4096]     = b2f(hv.y) + sc * acc[mt][nt][1];
            out[base + 2 * 4096] = b2f(hv.z) + sc * acc[mt][nt][2];
            out[base + 3 * 4096] = b2f(hv.w) + sc * acc[mt][nt][3];
        }
    }
#undef STAGEF
}

// ---------------------------------------------------------------------------
extern "C" void kernel_launch(void* const* d_in, const int* in_sizes, int n_in,
                              void* d_out, int out_size, void* d_ws, size_t ws_size,
                              hipStream_t stream)
{
    const float* x      = (const float*)d_in[0];
    const float* weight = (const float*)d_in[1];
    const float* bias   = (const float*)d_in[2];
    const float* w_down = (const float*)d_in[3];
    const float* w_up   = (const float*)d_in[4];
    const float* scale  = (const float*)d_in[5];
    const float* offset = (const float*)d_in[6];
    char* ws = (char*)d_ws;
    unsigned short* Cc    = (unsigned short*)(ws + 0);
    unsigned short* Wr2   = (unsigned short*)(ws + 25165824);
    unsigned short* W2    = (unsigned short*)(ws + 27377664);
    uint32_t*       oI    = (uint32_t*)(ws + 27869184);
    float*          oWt   = (float*)(ws + 28164096);
    unsigned short* Xb    = (unsigned short*)(ws + 28758016);
    unsigned short* Z     = (unsigned short*)(ws + 39909376);
    float* out = (float*)d_out;

    hipLaunchKernelGGL(k_prep, dim3(2194), dim3(256), 0, stream,
                       offset, weight, w_down, w_up, x, oI, oWt, Wr2, W2, Xb);
    hipLaunchKernelGGL(k_zgemm, dim3(128, 18), dim3(256), 0, stream,
                       Xb, Wr2, Z);
    hipLaunchKernelGGL(k_blend, dim3(40, 4), dim3(1024), 0, stream,
                       Z, oI, oWt, bias, Cc);
    hipLaunchKernelGGL(k_final, dim3(256, 2), dim3(256), 0, stream,
                       W2, Cc, scale, out);
}

// Round 14
// 178.365 us; speedup vs baseline: 1.2114x; 1.1477x over previous
//
#include <hip/hip_runtime.h>
#include <stdint.h>

// B=4, C=O=320, H=W=64 -> HW=4096, N=16384 (b*4096+px), N2=32768 for Cc.
// Round 14 = REVERT to round-11 best (177.6 us), per r13 pre-commitment.
// r12 (sp-split LDS blend): 4x plane re-stage -> HBM-bound, 66us. FAILED.
// r13 (staged-once LDS blend): 160 blocks = 1 blk/CU, no overlap, 52us. FAILED.
// r11 blend (scattered-L3 gather @ 10 blk/CU) measured ~40us = the L2/L3
// scattered-16B service-rate ceiling (~1.2 loads/cy/CU); both alternative
// decompositions measured worse -> blend is at its floor.
//   Z[(k,o), n] = sum_c w[o,c,k] x[c,n]   (GEMM: M=2880, N=16384, K=320)
//   dconv[o,p]  = sum_k sum_t wt_t(k,p) Z_k[o, idx_t(k,p)]      (k_blend)
//   h[o,p]      = sum_k Z_k[o, shift_k(p)] (conv3x3 = free from Z)
//
// Layouts:
//   Wr2 packed-8 K-major: elem(m,c) at ((c>>3)*2880 + m)*8 + (c&7), m=k*320+o.
//   Xb  packed-8:         elem(c,n) at ((c>>3)*16384 + n)*8 + (c&7).
//   Z   packed-8:         elem(m,n) at ((m>>3)*16384 + n)*8 + (m&7).
//   Cc  packed-8:         elem(o,n2) at (o>>3)*32768*8 + n2*8 + (o&7);
//                         n2<16384 dconv+bias, n2>=16384 h+bias.
//   oIdx: 2 u32 per (k,p); oW: float4 weights (validity folded).
//
// ws layout (bytes):
//   Cc 0..25,165,824 | Wr2 ..27,377,664 | W2 ..27,869,184 | oIdx ..28,164,096
//   oWt ..28,753,920 | Xb @28,758,016 | Z @39,909,376 (+94,371,840)

typedef __attribute__((ext_vector_type(4))) float f32x4;
typedef __attribute__((ext_vector_type(8))) short bf16x8;

typedef __attribute__((address_space(1))) const unsigned int uint_as1;
typedef __attribute__((address_space(3))) unsigned int uint_as3;

__device__ __forceinline__ void gl_lds16(const void* g, void* l) {
    __builtin_amdgcn_global_load_lds((uint_as1*)g, (uint_as3*)l, 16, 0, 0);
}

__device__ __forceinline__ unsigned short f2b(float f) {
    union { float f; uint32_t u; } v; v.f = f;
    uint32_t r = (v.u + 0x7FFFu + ((v.u >> 16) & 1u)) >> 16;
    return (unsigned short)r;
}
__device__ __forceinline__ float b2f(unsigned short h) {
    union { uint32_t u; float f; } v; v.u = ((uint32_t)h) << 16;
    return v.f;
}
__device__ __forceinline__ float b2f_lo(uint32_t u) {
    union { uint32_t u; float f; } v; v.u = u << 16;
    return v.f;
}
__device__ __forceinline__ float b2f_hi(uint32_t u) {
    union { uint32_t u; float f; } v; v.u = u & 0xFFFF0000u;
    return v.f;
}
__device__ __forceinline__ uint32_t pack2(float lo, float hi) {
    return (uint32_t)f2b(lo) | ((uint32_t)f2b(hi) << 16);
}

#define TAP8(AC, tv, wvx) \
    AC[0] += wvx * b2f_lo((uint32_t)tv.x); AC[1] += wvx * b2f_hi((uint32_t)tv.x); \
    AC[2] += wvx * b2f_lo((uint32_t)tv.y); AC[3] += wvx * b2f_hi((uint32_t)tv.y); \
    AC[4] += wvx * b2f_lo((uint32_t)tv.z); AC[5] += wvx * b2f_hi((uint32_t)tv.z); \
    AC[6] += wvx * b2f_lo((uint32_t)tv.w); AC[7] += wvx * b2f_hi((uint32_t)tv.w);

// ---------------------------------------------------------------------------
// Fused prep. [0,144) bilinear recs; [144,594) Wr2 (ushort8 coalesced);
// [594,1554) W2 (float4-vectorized reduce); [1554,2194) x->Xb pack.
__global__ __launch_bounds__(256) void k_prep(const float* __restrict__ off,
                                              const float* __restrict__ w,
                                              const float* __restrict__ wd,
                                              const float* __restrict__ wu,
                                              const float* __restrict__ x,
                                              uint32_t* __restrict__ oIdx,
                                              float* __restrict__ oW,
                                              unsigned short* __restrict__ Wr2,
                                              unsigned short* __restrict__ W2,
                                              unsigned short* __restrict__ Xb)
{
    const int bx = blockIdx.x, tid = threadIdx.x;
    if (bx < 144) {
        int gid = bx * 256 + tid;                    // 9*4096 exact
        int k = gid >> 12;
        int p = gid & 4095;
        int i = p >> 6, j = p & 63;
        float dy = off[(2 * k) * 4096 + p];
        float dx = off[(2 * k + 1) * 4096 + p];
        float py = (float)(i - 1 + k / 3) + dy;
        float px = (float)(j - 1 + k % 3) + dx;
        float fy = floorf(py), fx = floorf(px);
        float wy = py - fy, wx = px - fx;
        fy = fminf(fmaxf(fy, -100.f), 100.f);
        fx = fminf(fmaxf(fx, -100.f), 100.f);
        int y0 = (int)fy, x0 = (int)fx;
        float vy0 = (y0 >= 0 && y0 < 64) ? 1.f : 0.f;
        float vy1 = (y0 >= -1 && y0 < 63) ? 1.f : 0.f;
        float vx0 = (x0 >= 0 && x0 < 64) ? 1.f : 0.f;
        float vx1 = (x0 >= -1 && x0 < 63) ? 1.f : 0.f;
        float w00 = (1.f - wy) * (1.f - wx) * vy0 * vx0;
        float w01 = (1.f - wy) * wx * vy0 * vx1;
        float w10 = wy * (1.f - wx) * vy1 * vx0;
        float w11 = wy * wx * vy1 * vx1;
        int ya = min(max(y0, 0), 63), yb = min(max(y0 + 1, 0), 63);
        int xa = min(max(x0, 0), 63), xb = min(max(x0 + 1, 0), 63);
        oIdx[gid * 2 + 0] = (uint32_t)(ya * 64 + xa) | ((uint32_t)(ya * 64 + xb) << 16);
        oIdx[gid * 2 + 1] = (uint32_t)(yb * 64 + xa) | ((uint32_t)(yb * 64 + xb) << 16);
        oW[gid * 4 + 0] = w00;
        oW[gid * 4 + 1] = w01;
        oW[gid * 4 + 2] = w10;
        oW[gid * 4 + 3] = w11;
    } else if (bx < 594) {
        // Wr2: one thread per (cb, m); m = k*320+o; coalesced ushort8 store.
        int gid = (bx - 144) * 256 + tid;            // 40*2880 exact
        int cb = gid / 2880, m = gid - cb * 2880;
        int k = m / 320, o = m - k * 320;
        float v[8];
        #pragma unroll
        for (int cl = 0; cl < 8; ++cl) {
            int c = cb * 8 + cl;
            v[cl] = w[((size_t)o * 320 + c) * 9 + k];
        }
        int4 st;
        st.x = (int)pack2(v[0], v[1]);
        st.y = (int)pack2(v[2], v[3]);
        st.z = (int)pack2(v[4], v[5]);
        st.w = (int)pack2(v[6], v[7]);
        *(int4*)(Wr2 + (size_t)gid * 8) = st;
    } else if (bx < 1554) {
        // W2 = wu @ wd, float4-vectorized over l (4 indep chains).
        int gid = (bx - 594) * 256 + tid;            // 384*640 exact
        int o = gid / 640, kk2 = gid % 640;
        float a0 = 0.f, a1 = 0.f, a2 = 0.f, a3 = 0.f;
        if (o < 320) {
            const float* wuo = wu + (size_t)o * 320;
            for (int l = 0; l < 320; l += 4) {
                float4 u4 = *(const float4*)(wuo + l);
                a0 += u4.x * wd[(size_t)(l + 0) * 640 + kk2];
                a1 += u4.y * wd[(size_t)(l + 1) * 640 + kk2];
                a2 += u4.z * wd[(size_t)(l + 2) * 640 + kk2];
                a3 += u4.w * wd[(size_t)(l + 3) * 640 + kk2];
            }
        }
        W2[(size_t)((kk2 >> 3) * 384 + o) * 8 + (kk2 & 7)] = f2b((a0 + a1) + (a2 + a3));
    } else {
        // Pack x -> Xb (bf16 packed-8): elem(c,n) at ((c>>3)*16384+n)*8+(c&7).
        int bz = bx - 1554;                          // 640 blocks
        int sp = bz & 3, rest = bz >> 2;
        int gl = rest % 40, b = rest / 40;
        const float* xb = x + ((size_t)b * 320 + gl * 8) * 4096;
        unsigned short* xpb = Xb + ((size_t)gl * 16384 + b * 4096) * 8;
        #pragma unroll
        for (int i = 0; i < 4; ++i) {
            int px = sp * 1024 + i * 256 + tid;
            float v0 = xb[0 * 4096 + px], v1 = xb[1 * 4096 + px];
            float v2 = xb[2 * 4096 + px], v3 = xb[3 * 4096 + px];
            float v4 = xb[4 * 4096 + px], v5 = xb[5 * 4096 + px];
            float v6 = xb[6 * 4096 + px], v7 = xb[7 * 4096 + px];
            int4 st;
            st.x = (int)pack2(v0, v1);
            st.y = (int)pack2(v2, v3);
            st.z = (int)pack2(v4, v5);
            st.w = (int)pack2(v6, v7);
            *(int4*)(xpb + (size_t)px * 8) = st;
        }
    }
}

// ---------------------------------------------------------------------------
// Z-GEMM (r10-verified): A-fragments global->VGPR (L2/L3-hot Wr2); B via
// dbuf LDS (32 KB). M=2880 (18x160), N=16384, K=320 as 5 BK=64 steps.
// BM=160, BN=128, 4 waves 2Mx2N, per-wave 80x64, acc 5x4. 3 blk/CU.
__global__ __launch_bounds__(256, 3) void k_zgemm(const unsigned short* __restrict__ Xb,
                                                  const unsigned short* __restrict__ Wr2,
                                                  unsigned short* __restrict__ Z)
{
    __shared__ __align__(16) unsigned short Bs[2][8 * 128 * 8];   // 2 x 16 KB
    const int tid = threadIdx.x;
    const int n0 = blockIdx.x * 128, m0 = blockIdx.y * 160;
    const int lane = tid & 63, w = tid >> 6;
    const int wm = w & 1, wn = w >> 1;
    const int quad = lane >> 4, nl = lane & 15;
    const unsigned short* Abase = Wr2 + ((size_t)quad * 2880 + m0 + wm * 80 + nl) * 8;

#define STAGE_B(buf, s1) do { \
    _Pragma("unroll") \
    for (int q_ = 0; q_ < 4; ++q_) { \
        int u_ = tid + q_ * 256; \
        int row_ = u_ >> 7, nn_ = n0 + (u_ & 127); \
        gl_lds16(Xb + ((size_t)((s1) * 8 + row_) * 16384 + nn_) * 8, &Bs[buf][u_ * 8]); \
    } \
} while (0)

    f32x4 acc[5][4];
    #pragma unroll
    for (int mt = 0; mt < 5; ++mt)
        #pragma unroll
        for (int nt = 0; nt < 4; ++nt)
            acc[mt][nt] = 0.f;

    STAGE_B(0, 0);
    asm volatile("s_waitcnt vmcnt(0)" ::: "memory");
    __builtin_amdgcn_s_barrier();
    __builtin_amdgcn_sched_barrier(0);

    for (int s = 0; s < 5; ++s) {
        const int p = s & 1, np = p ^ 1;
        bf16x8 a[2][5];
        #pragma unroll
        for (int kc = 0; kc < 2; ++kc)
            #pragma unroll
            for (int mt = 0; mt < 5; ++mt)
                a[kc][mt] = *(const bf16x8*)(Abase
                    + ((size_t)((s * 8 + kc * 4) * 2880) + mt * 16) * 8);
        if (s < 4) STAGE_B(np, s + 1);
        __builtin_amdgcn_sched_barrier(0);
        #pragma unroll
        for (int kc = 0; kc < 2; ++kc) {
            bf16x8 bf[4];
            #pragma unroll
            for (int nt = 0; nt < 4; ++nt)
                bf[nt] = *(const bf16x8*)&Bs[p][((kc * 4 + quad) * 128 + wn * 64 + nt * 16 + nl) * 8];
            #pragma unroll
            for (int mt = 0; mt < 5; ++mt)
                #pragma unroll
                for (int nt = 0; nt < 4; ++nt)
                    acc[mt][nt] = __builtin_amdgcn_mfma_f32_16x16x32_bf16(a[kc][mt], bf[nt], acc[mt][nt], 0, 0, 0);
        }
        asm volatile("s_waitcnt vmcnt(0)" ::: "memory");
        __builtin_amdgcn_s_barrier();
        __builtin_amdgcn_sched_barrier(0);
    }

    // Epilogue: pack to Z (no bias). m index in [0,2880).
    #pragma unroll
    for (int mt = 0; mt < 5; ++mt) {
        int o0m = m0 + wm * 80 + mt * 16 + quad * 4;
        #pragma unroll
        for (int nt = 0; nt < 4; ++nt) {
            int n2 = n0 + wn * 64 + nt * 16 + nl;
            unsigned short* pp = Z + ((size_t)(o0m >> 3) * 16384 + n2) * 8 + (o0m & 7);
            ushort4 st;
            st.x = f2b(acc[mt][nt][0]);
            st.y = f2b(acc[mt][nt][1]);
            st.z = f2b(acc[mt][nt][2]);
            st.w = f2b(acc[mt][nt][3]);
            *(ushort4*)pp = st;
        }
    }
#undef STAGE_B
}

// ---------------------------------------------------------------------------
// Blend (r11-verified best): 1 og per thread, grid (16, 40, 4) = 2560
// blocks = 10 blk/CU. Scattered-L3 gather at the service-rate ceiling.
// Cc dconv-half = sum_k 4-tap bilinear of Z_k (+bias);
// Cc h-half     = sum_k shifted Z_k (conv3x3, zero-pad) (+bias).
__global__ __launch_bounds__(256) void k_blend(const unsigned short* __restrict__ Z,
                                               const uint32_t* __restrict__ oIdx,
                                               const float* __restrict__ oW,
                                               const float* __restrict__ bias,
                                               unsigned short* __restrict__ Cc)
{
    const int tid = threadIdx.x;
    const int px = blockIdx.x * 256 + tid;
    const int og = blockIdx.y;
    const int b = blockIdx.z;
    const int r = px >> 6, c0 = px & 63;

    float ac[8], ah[8];
    {
        float4 b0 = *(const float4*)&bias[og * 8];
        float4 b1 = *(const float4*)&bias[og * 8 + 4];
        ac[0] = b0.x; ac[1] = b0.y; ac[2] = b0.z; ac[3] = b0.w;
        ac[4] = b1.x; ac[5] = b1.y; ac[6] = b1.z; ac[7] = b1.w;
        #pragma unroll
        for (int j = 0; j < 8; ++j) ah[j] = ac[j];
    }
    #pragma unroll
    for (int k = 0; k < 9; ++k) {
        int gi = (k << 12) + px;
        uint32_t i0 = oIdx[gi * 2];
        uint32_t i1 = oIdx[gi * 2 + 1];
        float4 wv = *(const float4*)&oW[(size_t)gi * 4];
        int rr = r + k / 3 - 1, cc = c0 + k % 3 - 1;
        bool valid = (rr >= 0) & (rr < 64) & (cc >= 0) & (cc < 64);
        int hidx = valid ? (rr * 64 + cc) : 0;
        float hw = valid ? 1.f : 0.f;
        const unsigned short* Zb = Z + ((size_t)(k * 40 + og) * 16384 + b * 4096) * 8;
        int4 t0 = *(const int4*)(Zb + (size_t)(i0 & 0xFFFFu) * 8);
        int4 t1 = *(const int4*)(Zb + (size_t)(i0 >> 16) * 8);
        int4 t2 = *(const int4*)(Zb + (size_t)(i1 & 0xFFFFu) * 8);
        int4 t3 = *(const int4*)(Zb + (size_t)(i1 >> 16) * 8);
        int4 th = *(const int4*)(Zb + (size_t)hidx * 8);
        TAP8(ac, t0, wv.x) TAP8(ac, t1, wv.y)
        TAP8(ac, t2, wv.z) TAP8(ac, t3, wv.w)
        TAP8(ah, th, hw)
    }
    int4 sd, sh;
    sd.x = (int)pack2(ac[0], ac[1]); sd.y = (int)pack2(ac[2], ac[3]);
    sd.z = (int)pack2(ac[4], ac[5]); sd.w = (int)pack2(ac[6], ac[7]);
    sh.x = (int)pack2(ah[0], ah[1]); sh.y = (int)pack2(ah[2], ah[3]);
    sh.z = (int)pack2(ah[4], ah[5]); sh.w = (int)pack2(ah[6], ah[7]);
    unsigned short* cp = Cc + ((size_t)og * 32768 + b * 4096 + px) * 8;
    *(int4*)cp = sd;
    *(int4*)(cp + 16384 * 8) = sh;
}

// ---------------------------------------------------------------------------
// Final: out = h + scale * (W2 x [dconv; h]), K=640 as 10 BK=64 steps.
// r2-style dbuf 2-phase, BM=160 x BN=64, 4 waves 2Mx2N, per-wave 80x32,
// acc 5x2. LDS 56 KB -> 2 blk/CU; grid 256x2 = 512 = 2/CU exact.
__global__ __launch_bounds__(256) void k_final(const unsigned short* __restrict__ W2,
                                               const unsigned short* __restrict__ Cc,
                                               const float* __restrict__ scale,
                                               float* __restrict__ out)
{
    __shared__ __align__(16) unsigned short As[2][8 * 160 * 8];   // 2 x 20 KB
    __shared__ __align__(16) unsigned short Bs[2][8 * 64 * 8];    // 2 x 8 KB
    const int tid = threadIdx.x;
    const int n0 = blockIdx.x * 64, m0 = blockIdx.y * 160;
    const int lane = tid & 63, w = tid >> 6;
    const int wm = w & 1, wn = w >> 1;
    const int quad = lane >> 4, nl = lane & 15;

#define STAGEF(buf, s1) do { \
    _Pragma("unroll") \
    for (int q_ = 0; q_ < 5; ++q_) { \
        int u_ = tid + q_ * 256; \
        int kq_ = u_ / 160, m_ = u_ - kq_ * 160; \
        gl_lds16(W2 + ((size_t)(((s1) * 8 + kq_) * 384 + m0 + m_)) * 8, &As[buf][u_ * 8]); \
    } \
    { \
        int h_off_ = ((s1) < 5) ? 0 : 16384; \
        int gq_ = ((s1) < 5) ? (s1) * 8 : ((s1) - 5) * 8; \
        _Pragma("unroll") \
        for (int q_ = 0; q_ < 2; ++q_) { \
            int u_ = tid + q_ * 256; \
            int row_ = u_ >> 6, nn_ = n0 + (u_ & 63); \
            gl_lds16(Cc + ((size_t)(gq_ + row_) * 32768 + h_off_ + nn_) * 8, &Bs[buf][u_ * 8]); \
        } \
    } \
} while (0)

    f32x4 acc[5][2];
    #pragma unroll
    for (int mt = 0; mt < 5; ++mt)
        #pragma unroll
        for (int nt = 0; nt < 2; ++nt)
            acc[mt][nt] = 0.f;

    STAGEF(0, 0);
    asm volatile("s_waitcnt vmcnt(0)" ::: "memory");
    __builtin_amdgcn_s_barrier();
    __builtin_amdgcn_sched_barrier(0);

    for (int s = 0; s < 10; ++s) {
        const int p = s & 1, np = p ^ 1;
        if (s < 9) STAGEF(np, s + 1);
        __builtin_amdgcn_sched_barrier(0);
        #pragma unroll
        for (int kc = 0; kc < 2; ++kc) {
            bf16x8 a[5], bf[2];
            #pragma unroll
            for (int mt = 0; mt < 5; ++mt)
                a[mt] = *(const bf16x8*)&As[p][((kc * 4 + quad) * 160 + wm * 80 + mt * 16 + nl) * 8];
            #pragma unroll
            for (int nt = 0; nt < 2; ++nt)
                bf[nt] = *(const bf16x8*)&Bs[p][((kc * 4 + quad) * 64 + wn * 32 + nt * 16 + nl) * 8];
            #pragma unroll
            for (int mt = 0; mt < 5; ++mt)
                #pragma unroll
                for (int nt = 0; nt < 2; ++nt)
                    acc[mt][nt] = __builtin_amdgcn_mfma_f32_16x16x32_bf16(a[mt], bf[nt], acc[mt][nt], 0, 0, 0);
        }
        asm volatile("s_waitcnt vmcnt(0)" ::: "memory");
        __builtin_amdgcn_s_barrier();
        __builtin_amdgcn_sched_barrier(0);
    }

    float sc = scale[0];
    #pragma unroll
    for (int mt = 0; mt < 5; ++mt) {
        int o0 = m0 + wm * 80 + mt * 16 + quad * 4;
        #pragma unroll
        for (int nt = 0; nt < 2; ++nt) {
            int n = n0 + wn * 32 + nt * 16 + nl;
            int b = n >> 12, px = n & 4095;
            ushort4 hv = *(const ushort4*)(Cc + ((size_t)(o0 >> 3) * 32768 + n + 16384) * 8 + (o0 & 7));
            size_t base = ((size_t)(b * 320 + o0)) * 4096 + px;
            out[base]            = b2f(hv.x) + sc * acc[mt][nt][0];
            out[base + 4096]     = b2f(hv.y) + sc * acc[mt][nt][1];
            out[base + 2 * 4096] = b2f(hv.z) + sc * acc[mt][nt][2];
            out[base + 3 * 4096] = b2f(hv.w) + sc * acc[mt][nt][3];
        }
    }
#undef STAGEF
}

// ---------------------------------------------------------------------------
extern "C" void kernel_launch(void* const* d_in, const int* in_sizes, int n_in,
                              void* d_out, int out_size, void* d_ws, size_t ws_size,
                              hipStream_t stream)
{
    const float* x      = (const float*)d_in[0];
    const float* weight = (const float*)d_in[1];
    const float* bias   = (const float*)d_in[2];
    const float* w_down = (const float*)d_in[3];
    const float* w_up   = (const float*)d_in[4];
    const float* scale  = (const float*)d_in[5];
    const float* offset = (const float*)d_in[6];
    char* ws = (char*)d_ws;
    unsigned short* Cc    = (unsigned short*)(ws + 0);
    unsigned short* Wr2   = (unsigned short*)(ws + 25165824);
    unsigned short* W2    = (unsigned short*)(ws + 27377664);
    uint32_t*       oI    = (uint32_t*)(ws + 27869184);
    float*          oWt   = (float*)(ws + 28164096);
    unsigned short* Xb    = (unsigned short*)(ws + 28758016);
    unsigned short* Z     = (unsigned short*)(ws + 39909376);
    float* out = (float*)d_out;

    hipLaunchKernelGGL(k_prep, dim3(2194), dim3(256), 0, stream,
                       offset, weight, w_down, w_up, x, oI, oWt, Wr2, W2, Xb);
    hipLaunchKernelGGL(k_zgemm, dim3(128, 18), dim3(256), 0, stream,
                       Xb, Wr2, Z);
    hipLaunchKernelGGL(k_blend, dim3(16, 40, 4), dim3(256), 0, stream,
                       Z, oI, oWt, bias, Cc);
    hipLaunchKernelGGL(k_final, dim3(256, 2), dim3(256), 0, stream,
                       W2, Cc, scale, out);
}